// Round 9
// baseline (402.149 us; speedup 1.0000x reference)
//
#include <hip/hip_runtime.h>
#include <stdint.h>

namespace {

constexpr int kB = 16;
constexpr int kC = 80;
constexpr int kNLev = 5;
constexpr int kTopK = 1000;
constexpr int kDets = 100;
constexpr int kNBins = 512;
constexpr int kCap = 6144;
constexpr float kScoreT = 0.2f;
constexpr float kNmsT = 0.6f;
constexpr int kChunk = 8192;
constexpr int kNTot = kNLev * kTopK;  // 5000
// chunks per image (8192 elems): L0:160, L1:40, L2:10, L3:3, L4:1 => 214
constexpr int kChunksPerImg = 214;

struct LvlPtrs {
  const float* reg[5];
  const float* anc[5];
};

struct ClsPtrs {
  const float* cls[5];
  const float* ctr[5];
};

// precise sigmoid — must match reference bits for stored keys
__device__ __forceinline__ float sigm(float x) {
  return 1.0f / (1.0f + expf(-x));
}
// fast sigmoid for selection only (v_exp + v_rcp)
__device__ __forceinline__ float sigm_fast(float x) {
  return __builtin_amdgcn_rcpf(1.0f + __expf(-x));
}

__device__ __forceinline__ void chunk_map(int c, int* L, int* ch) {
  if (c < 160)      { *L = 0; *ch = c; }
  else if (c < 200) { *L = 1; *ch = c - 160; }
  else if (c < 210) { *L = 2; *ch = c - 200; }
  else if (c < 213) { *L = 3; *ch = c - 210; }
  else              { *L = 4; *ch = 0; }
}

// async global->LDS, 16B per lane; LDS dest = wave-uniform base + lane*16
__device__ __forceinline__ void gload16(const float* g, float* l) {
  __builtin_amdgcn_global_load_lds(
      (const __attribute__((address_space(1))) unsigned int*)g,
      (__attribute__((address_space(3))) unsigned int*)l, 16, 0, 0);
}

// ---- pass 1: approx-score histogram -> global atomic hist per (b,L) ----
__global__ void __launch_bounds__(256)
khist_all(ClsPtrs CP, unsigned int* __restrict__ ghist) {
  const int b = blockIdx.x / kChunksPerImg;
  const int c = blockIdx.x % kChunksPerImg;
  int L, ch; chunk_map(c, &L, &ch);
  const int HW = 16384 >> (2 * L);
  const int N = HW * kC;
  const int start = ch * kChunk;
  const int end = (start + kChunk < N) ? (start + kChunk) : N;
  const int nr = (end - start) >> 10;  // rounds of 1024 elems: 8 (hot), 5, or 4
  __shared__ float lcls[kChunk];       // 32 KB staged chunk
  __shared__ float lsct[136];          // sigm_fast(ctr) per location
  __shared__ unsigned int lh[kNBins];
  const float* clsb = CP.cls[L] + (size_t)b * N;
  const float* ctrb = CP.ctr[L] + (size_t)b * HW;
  const int wave = (int)threadIdx.x >> 6;
  const int lane = (int)threadIdx.x & 63;
  // issue all async stages back-to-back (cannot be serialized by regalloc)
  for (int r = 0; r < nr; ++r) {
    const int eo = r * 1024 + wave * 256;
    gload16(clsb + (start + eo + lane * 4), &lcls[eo]);
  }
  for (int i = threadIdx.x; i < kNBins; i += 256) lh[i] = 0;
  const int locb = start / kC;
  const int nloc = (end - 1) / kC - locb + 1;  // <= 104
  if ((int)threadIdx.x < nloc)
    lsct[threadIdx.x] = sigm_fast(ctrb[locb + (int)threadIdx.x]);
  __syncthreads();  // drains vmcnt(0): staged data + lh/lsct visible
  const int tid4 = (int)threadIdx.x * 4;
  for (int k = 0; k < nr; ++k) {
    const int eo = k * 1024 + tid4;
    const float4 v = *reinterpret_cast<const float4*>(&lcls[eo]);  // ds_read_b128
    const int e = start + eo;
    const int loc0 = (int)((unsigned)e / 80u);
    const int c0 = e - loc0 * kC;
    const int i0 = loc0 - locb;
    const float st0 = lsct[i0];
    const float st1 = lsct[i0 + 1];  // valid whenever used (crossing element staged)
    const float f[4] = {v.x, v.y, v.z, v.w};
#pragma unroll
    for (int q = 0; q < 4; ++q) {
      float st = (c0 + q >= kC) ? st1 : st0;
      float sc = __builtin_amdgcn_sqrtf(sigm_fast(f[q]) * st);
      int bin = (int)((sc - kScoreT) * 640.0f);
      if (bin >= 0) {
        if (bin > kNBins - 1) bin = kNBins - 1;
        atomicAdd(&lh[bin], 1u);
      }
    }
  }
  __syncthreads();
  const int g = b * kNLev + L;
  unsigned int* gh = ghist + (size_t)g * kNBins;
  for (int i = threadIdx.x; i < kNBins; i += 256)
    if (lh[i]) atomicAdd(&gh[i], lh[i]);
}

// ---- find cutoff bin (suffix >= TOPK) ----
__global__ void __launch_bounds__(256)
kcutoff(const unsigned int* __restrict__ ghist, int* __restrict__ cutoff) {
  const int g = blockIdx.x;
  const unsigned int* h = ghist + (size_t)g * kNBins;
  __shared__ unsigned int lh[kNBins];
  lh[threadIdx.x] = h[threadIdx.x];
  lh[256 + threadIdx.x] = h[256 + threadIdx.x];
  __syncthreads();
  if (threadIdx.x == 0) {
    unsigned int acc = 0; int cut = 0;
    for (int bin = kNBins - 1; bin >= 0; --bin) {
      acc += lh[bin];
      if (acc >= (unsigned)kTopK) { cut = bin; break; }
    }
    cutoff[g] = cut;
  }
}

// ---- pass 2: approx prefilter (relaxed 2 bins) -> element index only ----
__global__ void __launch_bounds__(256)
kcompact_all(ClsPtrs CP, const int* __restrict__ cutoff, unsigned int* __restrict__ cnt,
             unsigned int* __restrict__ candidx) {
  const int b = blockIdx.x / kChunksPerImg;
  const int c = blockIdx.x % kChunksPerImg;
  int L, ch; chunk_map(c, &L, &ch);
  const int HW = 16384 >> (2 * L);
  const int N = HW * kC;
  const int start = ch * kChunk;
  const int end = (start + kChunk < N) ? (start + kChunk) : N;
  const int nr = (end - start) >> 10;
  const int g = b * kNLev + L;
  // relaxed threshold: cut-2 bins, floored just below 0.2
  float thr = kScoreT + (float)(cutoff[g] - 2) * (1.0f / 640.0f);
  if (thr < 0.199f) thr = 0.199f;
  __shared__ float lcls[kChunk];
  __shared__ float lsct[136];
  const float* clsb = CP.cls[L] + (size_t)b * N;
  const float* ctrb = CP.ctr[L] + (size_t)b * HW;
  unsigned int* gi = candidx + (size_t)g * kCap;
  const int wave = (int)threadIdx.x >> 6;
  const int lane = (int)threadIdx.x & 63;
  for (int r = 0; r < nr; ++r) {
    const int eo = r * 1024 + wave * 256;
    gload16(clsb + (start + eo + lane * 4), &lcls[eo]);
  }
  const int locb = start / kC;
  const int nloc = (end - 1) / kC - locb + 1;
  if ((int)threadIdx.x < nloc)
    lsct[threadIdx.x] = sigm_fast(ctrb[locb + (int)threadIdx.x]);
  __syncthreads();
  const int tid4 = (int)threadIdx.x * 4;
  for (int k = 0; k < nr; ++k) {
    const int eo = k * 1024 + tid4;
    const float4 v = *reinterpret_cast<const float4*>(&lcls[eo]);
    const int e = start + eo;
    const int loc0 = (int)((unsigned)e / 80u);
    const int c0 = e - loc0 * kC;
    const int i0 = loc0 - locb;
    const float st0 = lsct[i0];
    const float st1 = lsct[i0 + 1];
    const float f[4] = {v.x, v.y, v.z, v.w};
#pragma unroll
    for (int q = 0; q < 4; ++q) {
      float st = (c0 + q >= kC) ? st1 : st0;
      float sa = __builtin_amdgcn_sqrtf(sigm_fast(f[q]) * st);
      if (sa >= thr) {  // rare (~0.2%)
        unsigned int slot = atomicAdd(&cnt[g], 1u);
        if (slot < (unsigned)kCap) gi[slot] = (unsigned int)(e + q);
      }
    }
  }
}

// ---- exact re-score of the ~1-3k survivors per group (precise bits) ----
__global__ void __launch_bounds__(256)
krescore(ClsPtrs CP, const unsigned int* __restrict__ cnt,
         const unsigned int* __restrict__ candidx,
         unsigned long long* __restrict__ cand) {
  const int gid = blockIdx.x * 256 + (int)threadIdx.x;
  const int g = gid / kCap;
  const int slot = gid - g * kCap;
  if (g >= kB * kNLev) return;
  unsigned int n = cnt[g]; if (n > (unsigned)kCap) n = kCap;
  if (slot >= (int)n) return;
  const unsigned int e = candidx[(size_t)g * kCap + slot];
  const int b = g / kNLev, L = g - (g / kNLev) * kNLev;
  const int HW = 16384 >> (2 * L);
  const int loc = (int)(e / 80u);
  const float cv = CP.cls[L][(size_t)b * HW * kC + e];
  const float tv = CP.ctr[L][(size_t)b * HW + loc];
  const float sex = sqrtf(sigm(cv) * sigm(tv));  // exact, matches ref bits
  const unsigned int inv = 0xFFFFFFu - (((unsigned)L << 21) | e);
  // sex <= 0.2 keys sort below all valid keys and are ignored downstream
  cand[(size_t)g * kCap + slot] =
      ((unsigned long long)__float_as_uint(sex) << 24) | inv;
}

// ---- per-(b,level) rank-scatter: sorted top-1000 without a sort ----
__global__ void __launch_bounds__(1024)
krankl(const unsigned long long* __restrict__ cand, const unsigned int* __restrict__ cnt,
       unsigned long long* __restrict__ lvlsorted) {
  const int g = blockIdx.x;
  const int l = g % kNLev;
  __shared__ unsigned long long s[kCap];
  unsigned int nu = cnt[g];
  const int n = (nu > (unsigned)kCap) ? kCap : (int)nu;
  for (int i = threadIdx.x; i < n; i += 1024)
    s[i] = cand[(size_t)g * kCap + i];
  __syncthreads();
  for (int p = n + (int)threadIdx.x; p < kTopK; p += 1024)
    lvlsorted[(size_t)g * kTopK + p] =
        (unsigned long long)(kNTot - (l * kTopK + p));
  for (int i = threadIdx.x; i < n; i += 1024) {
    const unsigned long long ki = s[i];
    int r = 0;
#pragma unroll 8
    for (int j = 0; j < n; ++j) r += (s[j] > ki) ? 1 : 0;
    if (r < kTopK) lvlsorted[(size_t)g * kTopK + r] = ki;
  }
}

__device__ __forceinline__ void decode_key(unsigned long long key, int b, const LvlPtrs& P,
                                           float4* box, int* label_out, float* score_out) {
  float sc = __uint_as_float((unsigned int)(key >> 24));
  *score_out = sc;
  if (!(sc > kScoreT)) { *box = make_float4(0.f, 0.f, 0.f, 0.f); *label_out = -1; return; }
  unsigned int pk = 0xFFFFFFu - (unsigned int)(key & 0xFFFFFFu);
  int l = pk >> 21;
  int idx = pk & 0x1FFFFF;
  int pos = idx / kC;
  int label = idx - pos * kC;
  int hw = 16384 >> (2 * l);
  const float* rg = P.reg[l] + ((size_t)b * hw + pos) * 4;
  const float* an = P.anc[l] + (size_t)pos * 4;
  float a0 = an[0], a1 = an[1], a2 = an[2], a3 = an[3];
  float cx = (a0 + a2) * 0.5f, cy = (a1 + a3) * 0.5f;
  float w = a2 - a0, h = a3 - a1;
  float x0 = cx - rg[0] * w, y0 = cy - rg[1] * h;
  float x1 = cx + rg[2] * w, y1 = cy + rg[3] * h;
  x0 = fminf(fmaxf(x0, 0.f), 1024.f);
  y0 = fminf(fmaxf(y0, 0.f), 1024.f);
  x1 = fminf(fmaxf(x1, 0.f), 1024.f);
  y1 = fminf(fmaxf(y1, 0.f), 1024.f);
  *box = make_float4(x0, y0, x1, y1);
  *label_out = label;
}

// ---- merge 5 sorted lists into global desc order via rank; decode offset boxes ----
__global__ void krank(const unsigned long long* __restrict__ lvlsorted,
                      unsigned long long* __restrict__ skey,
                      float4* __restrict__ obox, LvlPtrs P) {
  int gid = blockIdx.x * blockDim.x + threadIdx.x;
  if (gid >= kB * kNTot) return;
  int b = gid / kNTot;
  int r0 = gid - b * kNTot;
  int a = r0 / kTopK, p = r0 - a * kTopK;
  const unsigned long long* base = lvlsorted + (size_t)b * kNTot;
  unsigned long long key = base[a * kTopK + p];
  int rank = p;
  for (int a2 = 0; a2 < kNLev; ++a2) {
    if (a2 == a) continue;
    const unsigned long long* lst = base + a2 * kTopK;
    int lo = 0, hi = kTopK;
    while (lo < hi) {
      int mid = (lo + hi) >> 1;
      if (lst[mid] > key) lo = mid + 1; else hi = mid;
    }
    rank += lo;
  }
  float4 box; int label; float sc;
  decode_key(key, b, P, &box, &label, &sc);
  float off = (sc > kScoreT) ? (float)label * 1025.0f : 0.0f;
  skey[(size_t)b * kNTot + rank] = key;
  obox[(size_t)b * kNTot + rank] =
      make_float4(box.x + off, box.y + off, box.z + off, box.w + off);
}

// ---- greedy NMS scan: one wave per image ----
__global__ void __launch_bounds__(64)
knms(const unsigned long long* __restrict__ skey, const float4* __restrict__ obox,
     LvlPtrs P, float* __restrict__ out) {
  const int b = blockIdx.x;
  const int lane = threadIdx.x;
  __shared__ float4 kbox[kDets];
  __shared__ float karea[kDets];
  __shared__ unsigned long long kkey[kDets];
  const unsigned long long* keys = skey + (size_t)b * kNTot;
  const float4* boxes = obox + (size_t)b * kNTot;
  int nkept = 0;
  for (int base = 0; base < kNTot && nkept < kDets; base += 64) {
    int j = base + lane;
    unsigned long long key = (j < kNTot) ? keys[j] : 0ull;
    float sc = __uint_as_float((unsigned int)(key >> 24));
    bool scval = (j < kNTot) && (sc > kScoreT);
    if (__ballot(scval) == 0ull) break;
    float4 bx = make_float4(0.f, 0.f, 0.f, 0.f);
    if (scval) bx = boxes[j];
    float area = (bx.z - bx.x) * (bx.w - bx.y);
    bool alive = scval;
    for (int k = 0; k < nkept; ++k) {
      float4 kb = kbox[k];
      float xx1 = fmaxf(kb.x, bx.x), yy1 = fmaxf(kb.y, bx.y);
      float xx2 = fminf(kb.z, bx.z), yy2 = fminf(kb.w, bx.w);
      float inter = fmaxf(xx2 - xx1, 0.f) * fmaxf(yy2 - yy1, 0.f);
      float iou = inter / (area + karea[k] - inter + 1e-9f);
      if (iou > kNmsT) alive = false;
    }
    unsigned long long mask = __ballot(alive);
    while (mask != 0ull && nkept < kDets) {
      int lead = (int)__builtin_ctzll(mask);
      float lx = __shfl(bx.x, lead);
      float ly = __shfl(bx.y, lead);
      float lz = __shfl(bx.z, lead);
      float lw = __shfl(bx.w, lead);
      float la = __shfl(area, lead);
      unsigned int khi = (unsigned int)__shfl((int)(key >> 32), lead);
      unsigned int klo = (unsigned int)__shfl((int)(key & 0xFFFFFFFFull), lead);
      if (lane == 0) {
        kbox[nkept] = make_float4(lx, ly, lz, lw);
        karea[nkept] = la;
        kkey[nkept] = (((unsigned long long)khi) << 32) | (unsigned long long)klo;
      }
      __syncthreads();
      ++nkept;
      float xx1 = fmaxf(lx, bx.x), yy1 = fmaxf(ly, bx.y);
      float xx2 = fminf(lz, bx.z), yy2 = fminf(lw, bx.w);
      float inter = fmaxf(xx2 - xx1, 0.f) * fmaxf(yy2 - yy1, 0.f);
      float iou = inter / (area + la - inter + 1e-9f);
      if (iou > kNmsT) alive = false;
      mask = __ballot(alive);
    }
  }
  for (int s = lane; s < kDets; s += 64) {
    float4 bo = make_float4(0.f, 0.f, 0.f, 0.f);
    float so = 0.f, lo = -1.f;
    if (s < nkept) {
      float4 box; int label; float sc;
      decode_key(kkey[s], b, P, &box, &label, &sc);
      bo = box; so = sc; lo = (float)label;
    }
    size_t bi = (size_t)b * kDets + s;
    out[bi * 4 + 0] = bo.x;
    out[bi * 4 + 1] = bo.y;
    out[bi * 4 + 2] = bo.z;
    out[bi * 4 + 3] = bo.w;
    out[(size_t)kB * kDets * 4 + bi] = so;
    out[(size_t)kB * kDets * 5 + bi] = lo;
  }
}

}  // namespace

extern "C" void kernel_launch(void* const* d_in, const int* in_sizes, int n_in,
                              void* d_out, int out_size, void* d_ws, size_t ws_size,
                              hipStream_t stream) {
  ClsPtrs CP; LvlPtrs P;
  for (int l = 0; l < 5; ++l) {
    CP.cls[l] = (const float*)d_in[4 * l + 0];
    CP.ctr[l] = (const float*)d_in[4 * l + 1];
    P.reg[l]  = (const float*)d_in[4 * l + 2];
    P.anc[l]  = (const float*)d_in[4 * l + 3];
  }

  const int nblk = kB * kChunksPerImg;  // 3424

  char* w = (char*)d_ws;
  unsigned int* hist = (unsigned int*)w;          w += (size_t)80 * kNBins * 4;  // 160 KB
  int* cutoff = (int*)w;                          w += 80 * 4;
  unsigned int* cnt = (unsigned int*)w;           w += 80 * 4;
  unsigned int* candidx = (unsigned int*)w;       w += (size_t)80 * kCap * 4;   // 1.97 MB
  unsigned long long* cand = (unsigned long long*)w;      w += (size_t)80 * kCap * 8;  // 3.93 MB
  unsigned long long* lvlsorted = (unsigned long long*)w; w += (size_t)80 * kTopK * 8; // 0.64 MB
  unsigned long long* skeyp = (unsigned long long*)w;     w += (size_t)kB * kNTot * 8; // 0.64 MB
  float4* oboxp = (float4*)w;                     w += (size_t)kB * kNTot * 16;        // 1.28 MB

  // zero hist + cutoff + cnt (contiguous)
  hipMemsetAsync(hist, 0, (size_t)80 * kNBins * 4 + 80 * 8, stream);

  khist_all<<<nblk, 256, 0, stream>>>(CP, hist);

  kcutoff<<<80, 256, 0, stream>>>(hist, cutoff);

  kcompact_all<<<nblk, 256, 0, stream>>>(CP, cutoff, cnt, candidx);

  krescore<<<(80 * kCap) / 256, 256, 0, stream>>>(CP, cnt, candidx, cand);

  krankl<<<80, 1024, 0, stream>>>(cand, cnt, lvlsorted);

  int rblocks = (kB * kNTot + 255) / 256;
  krank<<<rblocks, 256, 0, stream>>>(lvlsorted, skeyp, oboxp, P);

  knms<<<kB, 64, 0, stream>>>(skeyp, oboxp, P, (float*)d_out);
}

// Round 10
// 306.230 us; speedup vs baseline: 1.3132x; 1.3132x over previous
//
#include <hip/hip_runtime.h>
#include <stdint.h>

namespace {

constexpr int kB = 16;
constexpr int kC = 80;
constexpr int kNLev = 5;
constexpr int kTopK = 1000;
constexpr int kDets = 100;
constexpr int kNBins = 512;
constexpr int kCap = 6144;
constexpr float kScoreT = 0.2f;
constexpr float kNmsT = 0.6f;
constexpr int kChunk = 8192;
constexpr int kNTot = kNLev * kTopK;  // 5000
// chunks per image (8192 elems): L0:160, L1:40, L2:10, L3:3, L4:1 => 214
constexpr int kChunksPerImg = 214;
constexpr int kGrid = 1712;  // persistent: each block does 2 chunks

struct LvlPtrs {
  const float* reg[5];
  const float* anc[5];
};

struct ClsPtrs {
  const float* cls[5];
  const float* ctr[5];
};

// precise sigmoid — must match reference bits for stored keys
__device__ __forceinline__ float sigm(float x) {
  return 1.0f / (1.0f + expf(-x));
}
// fast sigmoid for selection only (v_exp + v_rcp)
__device__ __forceinline__ float sigm_fast(float x) {
  return __builtin_amdgcn_rcpf(1.0f + __expf(-x));
}

__device__ __forceinline__ void chunk_map(int c, int* L, int* ch) {
  if (c < 160)      { *L = 0; *ch = c; }
  else if (c < 200) { *L = 1; *ch = c - 160; }
  else if (c < 210) { *L = 2; *ch = c - 200; }
  else if (c < 213) { *L = 3; *ch = c - 210; }
  else              { *L = 4; *ch = 0; }
}

// ---- pass 1: approx-score histogram -> global atomic hist per (b,L) ----
__global__ void __launch_bounds__(256)
khist_all(ClsPtrs CP, unsigned int* __restrict__ ghist) {
  __shared__ unsigned int lh[kNBins];
  for (int u = blockIdx.x; u < kB * kChunksPerImg; u += kGrid) {
    const int b = u / kChunksPerImg;
    const int c = u % kChunksPerImg;
    int L, ch; chunk_map(c, &L, &ch);
    const int HW = 16384 >> (2 * L);
    const int N = HW * kC;
    const int start = ch * kChunk;
    const int end = (start + kChunk < N) ? (start + kChunk) : N;
    const int nr = (end - start) >> 10;  // 8 (hot), 5, or 4
    for (int i = threadIdx.x; i < kNBins; i += 256) lh[i] = 0;
    __syncthreads();
    const float* clsb = CP.cls[L] + (size_t)b * N;
    const float* ctrb = CP.ctr[L] + (size_t)b * HW;
    const int tid4 = (int)threadIdx.x * 4;
    if (nr == 8) {
      // 1-deep prefetch pipeline: cls float4 + ctr pair for next round
      int e = start + tid4;
      float4 nxt = *reinterpret_cast<const float4*>(clsb + e);
      int lo = (int)((unsigned)e / 80u);
      float tc0 = ctrb[lo];
      float tc1 = ctrb[(lo + 1 < HW) ? lo + 1 : HW - 1];
#pragma unroll 1
      for (int k = 0; k < 8; ++k) {
        const float4 v = nxt;
        const int ecur = e;
        const int loc0 = lo;
        const float t0 = tc0, t1 = tc1;
        e += 1024;
        if (k < 7) {
          nxt = *reinterpret_cast<const float4*>(clsb + e);
          lo = (int)((unsigned)e / 80u);
          tc0 = ctrb[lo];
          tc1 = ctrb[(lo + 1 < HW) ? lo + 1 : HW - 1];
        }
        const int c0 = ecur - loc0 * kC;
        const float st0 = sigm_fast(t0);
        const float st1 = sigm_fast(t1);
        const float f[4] = {v.x, v.y, v.z, v.w};
#pragma unroll
        for (int q = 0; q < 4; ++q) {
          float st = (c0 + q >= kC) ? st1 : st0;
          float sc = __builtin_amdgcn_sqrtf(sigm_fast(f[q]) * st);
          int bin = (int)((sc - kScoreT) * 640.0f);
          if (bin >= 0) {
            if (bin > kNBins - 1) bin = kNBins - 1;
            atomicAdd(&lh[bin], 1u);
          }
        }
      }
    } else {
      for (int k = 0; k < nr; ++k) {
        const int e = start + k * 1024 + tid4;
        const int loc0 = (int)((unsigned)e / 80u);
        const int c0 = e - loc0 * kC;
        const int loc1 = (loc0 + 1 < HW) ? loc0 + 1 : HW - 1;
        const float st0 = sigm_fast(ctrb[loc0]);
        const float st1 = sigm_fast(ctrb[loc1]);
        const float4 v = *reinterpret_cast<const float4*>(clsb + e);
        const float f[4] = {v.x, v.y, v.z, v.w};
#pragma unroll
        for (int q = 0; q < 4; ++q) {
          float st = (c0 + q >= kC) ? st1 : st0;
          float sc = __builtin_amdgcn_sqrtf(sigm_fast(f[q]) * st);
          int bin = (int)((sc - kScoreT) * 640.0f);
          if (bin >= 0) {
            if (bin > kNBins - 1) bin = kNBins - 1;
            atomicAdd(&lh[bin], 1u);
          }
        }
      }
    }
    __syncthreads();
    const int g = b * kNLev + L;
    unsigned int* gh = ghist + (size_t)g * kNBins;
    for (int i = threadIdx.x; i < kNBins; i += 256)
      if (lh[i]) atomicAdd(&gh[i], lh[i]);
    __syncthreads();
  }
}

// ---- find cutoff bin (suffix >= TOPK) ----
__global__ void __launch_bounds__(256)
kcutoff(const unsigned int* __restrict__ ghist, int* __restrict__ cutoff) {
  const int g = blockIdx.x;
  const unsigned int* h = ghist + (size_t)g * kNBins;
  __shared__ unsigned int lh[kNBins];
  lh[threadIdx.x] = h[threadIdx.x];
  lh[256 + threadIdx.x] = h[256 + threadIdx.x];
  __syncthreads();
  if (threadIdx.x == 0) {
    unsigned int acc = 0; int cut = 0;
    for (int bin = kNBins - 1; bin >= 0; --bin) {
      acc += lh[bin];
      if (acc >= (unsigned)kTopK) { cut = bin; break; }
    }
    cutoff[g] = cut;
  }
}

// ---- pass 2: approx prefilter (relaxed 2 bins) -> element index only ----
__global__ void __launch_bounds__(256)
kcompact_all(ClsPtrs CP, const int* __restrict__ cutoff, unsigned int* __restrict__ cnt,
             unsigned int* __restrict__ candidx) {
  for (int u = blockIdx.x; u < kB * kChunksPerImg; u += kGrid) {
    const int b = u / kChunksPerImg;
    const int c = u % kChunksPerImg;
    int L, ch; chunk_map(c, &L, &ch);
    const int HW = 16384 >> (2 * L);
    const int N = HW * kC;
    const int start = ch * kChunk;
    const int end = (start + kChunk < N) ? (start + kChunk) : N;
    const int nr = (end - start) >> 10;
    const int g = b * kNLev + L;
    // relaxed threshold: cut-2 bins, floored just below 0.2
    float thr = kScoreT + (float)(cutoff[g] - 2) * (1.0f / 640.0f);
    if (thr < 0.199f) thr = 0.199f;
    const float* clsb = CP.cls[L] + (size_t)b * N;
    const float* ctrb = CP.ctr[L] + (size_t)b * HW;
    unsigned int* gi = candidx + (size_t)g * kCap;
    const int tid4 = (int)threadIdx.x * 4;
    if (nr == 8) {
      int e = start + tid4;
      float4 nxt = *reinterpret_cast<const float4*>(clsb + e);
      int lo = (int)((unsigned)e / 80u);
      float tc0 = ctrb[lo];
      float tc1 = ctrb[(lo + 1 < HW) ? lo + 1 : HW - 1];
#pragma unroll 1
      for (int k = 0; k < 8; ++k) {
        const float4 v = nxt;
        const int ecur = e;
        const int loc0 = lo;
        const float t0 = tc0, t1 = tc1;
        e += 1024;
        if (k < 7) {
          nxt = *reinterpret_cast<const float4*>(clsb + e);
          lo = (int)((unsigned)e / 80u);
          tc0 = ctrb[lo];
          tc1 = ctrb[(lo + 1 < HW) ? lo + 1 : HW - 1];
        }
        const int c0 = ecur - loc0 * kC;
        const float st0 = sigm_fast(t0);
        const float st1 = sigm_fast(t1);
        const float f[4] = {v.x, v.y, v.z, v.w};
#pragma unroll
        for (int q = 0; q < 4; ++q) {
          float st = (c0 + q >= kC) ? st1 : st0;
          float sa = __builtin_amdgcn_sqrtf(sigm_fast(f[q]) * st);
          if (sa >= thr) {  // rare (~0.2%)
            unsigned int slot = atomicAdd(&cnt[g], 1u);
            if (slot < (unsigned)kCap) gi[slot] = (unsigned int)(ecur + q);
          }
        }
      }
    } else {
      for (int k = 0; k < nr; ++k) {
        const int e = start + k * 1024 + tid4;
        const int loc0 = (int)((unsigned)e / 80u);
        const int c0 = e - loc0 * kC;
        const int loc1 = (loc0 + 1 < HW) ? loc0 + 1 : HW - 1;
        const float st0 = sigm_fast(ctrb[loc0]);
        const float st1 = sigm_fast(ctrb[loc1]);
        const float4 v = *reinterpret_cast<const float4*>(clsb + e);
        const float f[4] = {v.x, v.y, v.z, v.w};
#pragma unroll
        for (int q = 0; q < 4; ++q) {
          float st = (c0 + q >= kC) ? st1 : st0;
          float sa = __builtin_amdgcn_sqrtf(sigm_fast(f[q]) * st);
          if (sa >= thr) {
            unsigned int slot = atomicAdd(&cnt[g], 1u);
            if (slot < (unsigned)kCap) gi[slot] = (unsigned int)(e + q);
          }
        }
      }
    }
  }
}

// ---- exact re-score of the ~1-3k survivors per group (precise bits) ----
__global__ void __launch_bounds__(256)
krescore(ClsPtrs CP, const unsigned int* __restrict__ cnt,
         const unsigned int* __restrict__ candidx,
         unsigned long long* __restrict__ cand) {
  const int gid = blockIdx.x * 256 + (int)threadIdx.x;
  const int g = gid / kCap;
  const int slot = gid - g * kCap;
  if (g >= kB * kNLev) return;
  unsigned int n = cnt[g]; if (n > (unsigned)kCap) n = kCap;
  if (slot >= (int)n) return;
  const unsigned int e = candidx[(size_t)g * kCap + slot];
  const int b = g / kNLev, L = g - (g / kNLev) * kNLev;
  const int HW = 16384 >> (2 * L);
  const int loc = (int)(e / 80u);
  const float cv = CP.cls[L][(size_t)b * HW * kC + e];
  const float tv = CP.ctr[L][(size_t)b * HW + loc];
  const float sex = sqrtf(sigm(cv) * sigm(tv));  // exact, matches ref bits
  const unsigned int inv = 0xFFFFFFu - (((unsigned)L << 21) | e);
  // sex <= 0.2 keys sort below all valid keys and are ignored downstream
  cand[(size_t)g * kCap + slot] =
      ((unsigned long long)__float_as_uint(sex) << 24) | inv;
}

// ---- per-(b,level) rank-scatter: sorted top-1000 without a sort ----
__global__ void __launch_bounds__(1024)
krankl(const unsigned long long* __restrict__ cand, const unsigned int* __restrict__ cnt,
       unsigned long long* __restrict__ lvlsorted) {
  const int g = blockIdx.x;
  const int l = g % kNLev;
  __shared__ unsigned long long s[kCap];
  unsigned int nu = cnt[g];
  const int n = (nu > (unsigned)kCap) ? kCap : (int)nu;
  for (int i = threadIdx.x; i < n; i += 1024)
    s[i] = cand[(size_t)g * kCap + i];
  __syncthreads();
  for (int p = n + (int)threadIdx.x; p < kTopK; p += 1024)
    lvlsorted[(size_t)g * kTopK + p] =
        (unsigned long long)(kNTot - (l * kTopK + p));
  for (int i = threadIdx.x; i < n; i += 1024) {
    const unsigned long long ki = s[i];
    int r = 0;
#pragma unroll 8
    for (int j = 0; j < n; ++j) r += (s[j] > ki) ? 1 : 0;
    if (r < kTopK) lvlsorted[(size_t)g * kTopK + r] = ki;
  }
}

__device__ __forceinline__ void decode_key(unsigned long long key, int b, const LvlPtrs& P,
                                           float4* box, int* label_out, float* score_out) {
  float sc = __uint_as_float((unsigned int)(key >> 24));
  *score_out = sc;
  if (!(sc > kScoreT)) { *box = make_float4(0.f, 0.f, 0.f, 0.f); *label_out = -1; return; }
  unsigned int pk = 0xFFFFFFu - (unsigned int)(key & 0xFFFFFFu);
  int l = pk >> 21;
  int idx = pk & 0x1FFFFF;
  int pos = idx / kC;
  int label = idx - pos * kC;
  int hw = 16384 >> (2 * l);
  const float* rg = P.reg[l] + ((size_t)b * hw + pos) * 4;
  const float* an = P.anc[l] + (size_t)pos * 4;
  float a0 = an[0], a1 = an[1], a2 = an[2], a3 = an[3];
  float cx = (a0 + a2) * 0.5f, cy = (a1 + a3) * 0.5f;
  float w = a2 - a0, h = a3 - a1;
  float x0 = cx - rg[0] * w, y0 = cy - rg[1] * h;
  float x1 = cx + rg[2] * w, y1 = cy + rg[3] * h;
  x0 = fminf(fmaxf(x0, 0.f), 1024.f);
  y0 = fminf(fmaxf(y0, 0.f), 1024.f);
  x1 = fminf(fmaxf(x1, 0.f), 1024.f);
  y1 = fminf(fmaxf(y1, 0.f), 1024.f);
  *box = make_float4(x0, y0, x1, y1);
  *label_out = label;
}

// ---- merge 5 sorted lists into global desc order via rank; decode offset boxes ----
__global__ void krank(const unsigned long long* __restrict__ lvlsorted,
                      unsigned long long* __restrict__ skey,
                      float4* __restrict__ obox, LvlPtrs P) {
  int gid = blockIdx.x * blockDim.x + threadIdx.x;
  if (gid >= kB * kNTot) return;
  int b = gid / kNTot;
  int r0 = gid - b * kNTot;
  int a = r0 / kTopK, p = r0 - a * kTopK;
  const unsigned long long* base = lvlsorted + (size_t)b * kNTot;
  unsigned long long key = base[a * kTopK + p];
  int rank = p;
  for (int a2 = 0; a2 < kNLev; ++a2) {
    if (a2 == a) continue;
    const unsigned long long* lst = base + a2 * kTopK;
    int lo = 0, hi = kTopK;
    while (lo < hi) {
      int mid = (lo + hi) >> 1;
      if (lst[mid] > key) lo = mid + 1; else hi = mid;
    }
    rank += lo;
  }
  float4 box; int label; float sc;
  decode_key(key, b, P, &box, &label, &sc);
  float off = (sc > kScoreT) ? (float)label * 1025.0f : 0.0f;
  skey[(size_t)b * kNTot + rank] = key;
  obox[(size_t)b * kNTot + rank] =
      make_float4(box.x + off, box.y + off, box.z + off, box.w + off);
}

// ---- greedy NMS scan: one wave per image ----
__global__ void __launch_bounds__(64)
knms(const unsigned long long* __restrict__ skey, const float4* __restrict__ obox,
     LvlPtrs P, float* __restrict__ out) {
  const int b = blockIdx.x;
  const int lane = threadIdx.x;
  __shared__ float4 kbox[kDets];
  __shared__ float karea[kDets];
  __shared__ unsigned long long kkey[kDets];
  const unsigned long long* keys = skey + (size_t)b * kNTot;
  const float4* boxes = obox + (size_t)b * kNTot;
  int nkept = 0;
  for (int base = 0; base < kNTot && nkept < kDets; base += 64) {
    int j = base + lane;
    unsigned long long key = (j < kNTot) ? keys[j] : 0ull;
    float sc = __uint_as_float((unsigned int)(key >> 24));
    bool scval = (j < kNTot) && (sc > kScoreT);
    if (__ballot(scval) == 0ull) break;
    float4 bx = make_float4(0.f, 0.f, 0.f, 0.f);
    if (scval) bx = boxes[j];
    float area = (bx.z - bx.x) * (bx.w - bx.y);
    bool alive = scval;
    for (int k = 0; k < nkept; ++k) {
      float4 kb = kbox[k];
      float xx1 = fmaxf(kb.x, bx.x), yy1 = fmaxf(kb.y, bx.y);
      float xx2 = fminf(kb.z, bx.z), yy2 = fminf(kb.w, bx.w);
      float inter = fmaxf(xx2 - xx1, 0.f) * fmaxf(yy2 - yy1, 0.f);
      float iou = inter / (area + karea[k] - inter + 1e-9f);
      if (iou > kNmsT) alive = false;
    }
    unsigned long long mask = __ballot(alive);
    while (mask != 0ull && nkept < kDets) {
      int lead = (int)__builtin_ctzll(mask);
      float lx = __shfl(bx.x, lead);
      float ly = __shfl(bx.y, lead);
      float lz = __shfl(bx.z, lead);
      float lw = __shfl(bx.w, lead);
      float la = __shfl(area, lead);
      unsigned int khi = (unsigned int)__shfl((int)(key >> 32), lead);
      unsigned int klo = (unsigned int)__shfl((int)(key & 0xFFFFFFFFull), lead);
      if (lane == 0) {
        kbox[nkept] = make_float4(lx, ly, lz, lw);
        karea[nkept] = la;
        kkey[nkept] = (((unsigned long long)khi) << 32) | (unsigned long long)klo;
      }
      __syncthreads();
      ++nkept;
      float xx1 = fmaxf(lx, bx.x), yy1 = fmaxf(ly, bx.y);
      float xx2 = fminf(lz, bx.z), yy2 = fminf(lw, bx.w);
      float inter = fmaxf(xx2 - xx1, 0.f) * fmaxf(yy2 - yy1, 0.f);
      float iou = inter / (area + la - inter + 1e-9f);
      if (iou > kNmsT) alive = false;
      mask = __ballot(alive);
    }
  }
  for (int s = lane; s < kDets; s += 64) {
    float4 bo = make_float4(0.f, 0.f, 0.f, 0.f);
    float so = 0.f, lo = -1.f;
    if (s < nkept) {
      float4 box; int label; float sc;
      decode_key(kkey[s], b, P, &box, &label, &sc);
      bo = box; so = sc; lo = (float)label;
    }
    size_t bi = (size_t)b * kDets + s;
    out[bi * 4 + 0] = bo.x;
    out[bi * 4 + 1] = bo.y;
    out[bi * 4 + 2] = bo.z;
    out[bi * 4 + 3] = bo.w;
    out[(size_t)kB * kDets * 4 + bi] = so;
    out[(size_t)kB * kDets * 5 + bi] = lo;
  }
}

}  // namespace

extern "C" void kernel_launch(void* const* d_in, const int* in_sizes, int n_in,
                              void* d_out, int out_size, void* d_ws, size_t ws_size,
                              hipStream_t stream) {
  ClsPtrs CP; LvlPtrs P;
  for (int l = 0; l < 5; ++l) {
    CP.cls[l] = (const float*)d_in[4 * l + 0];
    CP.ctr[l] = (const float*)d_in[4 * l + 1];
    P.reg[l]  = (const float*)d_in[4 * l + 2];
    P.anc[l]  = (const float*)d_in[4 * l + 3];
  }

  char* w = (char*)d_ws;
  unsigned int* hist = (unsigned int*)w;          w += (size_t)80 * kNBins * 4;  // 160 KB
  int* cutoff = (int*)w;                          w += 80 * 4;
  unsigned int* cnt = (unsigned int*)w;           w += 80 * 4;
  unsigned int* candidx = (unsigned int*)w;       w += (size_t)80 * kCap * 4;   // 1.97 MB
  unsigned long long* cand = (unsigned long long*)w;      w += (size_t)80 * kCap * 8;  // 3.93 MB
  unsigned long long* lvlsorted = (unsigned long long*)w; w += (size_t)80 * kTopK * 8; // 0.64 MB
  unsigned long long* skeyp = (unsigned long long*)w;     w += (size_t)kB * kNTot * 8; // 0.64 MB
  float4* oboxp = (float4*)w;                     w += (size_t)kB * kNTot * 16;        // 1.28 MB

  // zero hist + cutoff + cnt (contiguous)
  hipMemsetAsync(hist, 0, (size_t)80 * kNBins * 4 + 80 * 8, stream);

  khist_all<<<kGrid, 256, 0, stream>>>(CP, hist);

  kcutoff<<<80, 256, 0, stream>>>(hist, cutoff);

  kcompact_all<<<kGrid, 256, 0, stream>>>(CP, cutoff, cnt, candidx);

  krescore<<<(80 * kCap) / 256, 256, 0, stream>>>(CP, cnt, candidx, cand);

  krankl<<<80, 1024, 0, stream>>>(cand, cnt, lvlsorted);

  int rblocks = (kB * kNTot + 255) / 256;
  krank<<<rblocks, 256, 0, stream>>>(lvlsorted, skeyp, oboxp, P);

  knms<<<kB, 64, 0, stream>>>(skeyp, oboxp, P, (float*)d_out);
}